// Round 4
// baseline (4372.137 us; speedup 1.0000x reference)
//
#include <hip/hip_runtime.h>
#include <stdint.h>

// RNN_29102698398007 — B=64, T=512, D=H=1024.  Inputs fp32, output fp32
// (bf16-leniency compare).  Evidence: r1/r2 bf16-read => NaN (fp32 mantissa
// bits decode as bf16 inf/NaN); r3 fp32-read+bf16-write => finite error
// exactly = ref-max over the unwritten half of the fp32 buffer.
//
//   gemm_xh  : xh = X @ Kw -> Y fp32 (in place of output)        [1 launch]
//   swz      : W_rec fp32 -> d_ws bf16, MFMA B-frag order        [1 launch]
//   step_k(s): h_s = sigmoid(xh_s + h_{s-1} @ W_rec), fp32 in-place [512 launches]
// Cross-step ordering via stream serialization. Correctness-first; the 512
// launches (launch-overhead-bound) are the next optimization target.

using short8 = __attribute__((ext_vector_type(8))) short;
using bf16x8 = __attribute__((ext_vector_type(8))) __bf16;
using f32x4  = __attribute__((ext_vector_type(4))) float;

typedef unsigned short u16;
typedef unsigned int   u32;

#define T_ 512
#define H_ 1024

__device__ __forceinline__ u16 f2bf(float f) {
    union { float f; u32 i; } v; v.f = f;
    u32 b = v.i + 0x7fffu + ((v.i >> 16) & 1u);   // RNE; finite values only
    return (u16)(b >> 16);
}
__device__ __forceinline__ f32x4 mfma_bf16_16x16x32(short8 a, short8 b, f32x4 c) {
    return __builtin_amdgcn_mfma_f32_16x16x32_bf16(
        __builtin_bit_cast(bf16x8, a), __builtin_bit_cast(bf16x8, b), c, 0, 0, 0);
}
__device__ __forceinline__ float sigmoidf(float z) {
    z = fminf(fmaxf(z, -30.f), 30.f);
    return 1.f / (1.f + __expf(-z));
}
__device__ __forceinline__ short8 cvt8(f32x4 a0, f32x4 a1) {
    short8 r;
    #pragma unroll
    for (int j = 0; j < 4; ++j) { r[j] = (short)f2bf(a0[j]); r[4 + j] = (short)f2bf(a1[j]); }
    return r;
}

// ---------------- k0: xh = X[32768,1024] @ Kw[1024,1024], fp32 -> fp32 ----------------
// 256 thr (4 waves). Tile M=64 (wave -> 16 rows), N=64, BK=32. B^T staged in LDS (bf16).
__global__ __launch_bounds__(256) void gemm_xh(const float* __restrict__ X,
                                               const float* __restrict__ Kw,
                                               float* __restrict__ Y)
{
    __shared__ alignas(16) u16 Bt[64][40];     // [n][k], k padded 32->40
    const int tid  = threadIdx.x;
    const int lane = tid & 63;
    const int wv   = tid >> 6;
    const int quad = lane >> 4;
    const int l16  = lane & 15;
    const int m0   = blockIdx.x * 64;
    const int n0   = blockIdx.y * 64;
    const int cB   = tid & 63;                 // staging: n within tile
    const int kg   = tid >> 6;                 // staging: k octet

    f32x4 acc[4] = {};

    for (int k0 = 0; k0 < H_; k0 += 32) {
        __syncthreads();
        short8 sv;
        #pragma unroll
        for (int jj = 0; jj < 8; ++jj)
            sv[jj] = (short)f2bf(Kw[(k0 + kg * 8 + jj) * H_ + n0 + cB]);
        *(short8*)&Bt[cB][kg * 8] = sv;
        __syncthreads();

        // A-frag: A[m=l16][k=quad*8+jj]
        const f32x4* p = (const f32x4*)&X[(m0 + wv * 16 + l16) * H_ + k0 + quad * 8];
        short8 av = cvt8(p[0], p[1]);
        #pragma unroll
        for (int nt = 0; nt < 4; ++nt) {
            // B-frag: B[k=quad*8+jj][n=l16] == Bt[n][k] contiguous 16B
            short8 bv = *(const short8*)&Bt[nt * 16 + l16][quad * 8];
            acc[nt] = mfma_bf16_16x16x32(av, bv, acc[nt]);
        }
    }
    // C/D: col = l16, row = quad*4 + r   [m89-verified]
    #pragma unroll
    for (int nt = 0; nt < 4; ++nt)
        #pragma unroll
        for (int r = 0; r < 4; ++r)
            Y[(m0 + wv * 16 + quad * 4 + r) * H_ + n0 + nt * 16 + l16] = acc[nt][r];
}

// ---------------- k1: swizzle W_rec (fp32) into bf16 B-frag order ----------------
// Wsw[t*8+jj], t = gj*4096 + wv*2048 + kt*64 + lane
//            = bf16( Kr[(kt*32 + (lane>>4)*8 + jj)*H + gj*32 + wv*16 + (lane&15)] )
__global__ __launch_bounds__(256) void swz(const float* __restrict__ Kr,
                                           u16* __restrict__ Wsw)
{
    const int t    = blockIdx.x * 256 + threadIdx.x;   // [0, 131072)
    const int lane = t & 63;
    const int kt   = (t >> 6) & 31;
    const int wv   = (t >> 11) & 1;
    const int gj   = t >> 12;
    const int quad = lane >> 4;
    const int l16  = lane & 15;
    const int col  = gj * 32 + wv * 16 + l16;
    short8 sv;
    #pragma unroll
    for (int jj = 0; jj < 8; ++jj)
        sv[jj] = (short)f2bf(Kr[(kt * 32 + quad * 8 + jj) * H_ + col]);
    *(short8*)&Wsw[t * 8] = sv;
}

// ---------------- k2: one scan step ----------------
// 128 wgs x 128 thr. wg(gi,gj): batch rows [16gi,16gi+16) x cols [32gj,32gj+32).
// h stored fp32 in Y; converted to bf16 A-frags on the fly.
template<bool SW>
__global__ __launch_bounds__(128) void step_k(float* __restrict__ Y,
                                              const void* __restrict__ Wsrc,
                                              int s)
{
    const int tid  = threadIdx.x;
    const int lane = tid & 63;
    const int wv   = tid >> 6;
    const int quad = lane >> 4;
    const int l16  = lane & 15;
    const int gi   = blockIdx.x >> 5;
    const int gj   = blockIdx.x & 31;
    const int colBase = gj * 32 + wv * 16;

    f32x4 acc = {};
    if (s > 0) {
        const int abase = ((gi * 16 + l16) * T_ + (s - 1)) * H_;
        #pragma unroll 4
        for (int j2 = 0; j2 < 32; ++j2) {
            const f32x4* ap = (const f32x4*)&Y[abase + j2 * 32 + quad * 8];
            short8 av = cvt8(ap[0], ap[1]);                 // h_{s-1} fp32 -> bf16 frag
            short8 bv;
            if (SW) {
                bv = *(const short8*)&((const u16*)Wsrc)[(((gj * 2 + wv) * 32 + j2) * 64 + lane) * 8];
            } else {
                const float* Krf = (const float*)Wsrc;
                #pragma unroll
                for (int jj = 0; jj < 8; ++jj)
                    bv[jj] = (short)f2bf(Krf[(j2 * 32 + quad * 8 + jj) * H_ + colBase + l16]);
            }
            acc = mfma_bf16_16x16x32(av, bv, acc);
        }
    }
    #pragma unroll
    for (int r = 0; r < 4; ++r) {
        const int idx = ((gi * 16 + quad * 4 + r) * T_ + s) * H_ + colBase + l16;
        float z = acc[r] + Y[idx];            // xh (fp32, from phase 1)
        Y[idx] = sigmoidf(z);                 // h (fp32, in place)
    }
}

extern "C" void kernel_launch(void* const* d_in, const int* in_sizes, int n_in,
                              void* d_out, int out_size, void* d_ws, size_t ws_size,
                              hipStream_t stream) {
    const float* X  = (const float*)d_in[0];   // x [64,512,1024] fp32
    const float* Kw = (const float*)d_in[1];   // kernel [1024,1024] fp32
    const float* Kr = (const float*)d_in[2];   // recurrent_kernel [1024,1024] fp32
    float* Y        = (float*)d_out;           // [64,512,1024] fp32 (xh, then h)

    gemm_xh<<<dim3(512, 16), dim3(256), 0, stream>>>(X, Kw, Y);

    const bool useSw = (ws_size >= (size_t)(2 * 1024 * 1024));
    if (useSw) {
        u16* Wsw = (u16*)d_ws;
        swz<<<dim3(512), dim3(256), 0, stream>>>(Kr, Wsw);
        for (int s = 0; s < T_; ++s)
            step_k<true><<<dim3(128), dim3(128), 0, stream>>>(Y, (const void*)Wsw, s);
    } else {
        for (int s = 0; s < T_; ++s)
            step_k<false><<<dim3(128), dim3(128), 0, stream>>>(Y, (const void*)Kr, s);
    }
}